// Round 5
// baseline (204.209 us; speedup 1.0000x reference)
//
#include <hip/hip_runtime.h>
#include <math.h>
#include <stdint.h>

typedef __bf16 bf16;
typedef __bf16 bf16x4 __attribute__((ext_vector_type(4)));
typedef __bf16 bf16x8 __attribute__((ext_vector_type(8)));
typedef float f32x4 __attribute__((ext_vector_type(4)));
typedef float f32x16 __attribute__((ext_vector_type(16)));

constexpr int E = 1024;   // embed dim
constexpr int S = 2048;   // seq len
constexpr int H = 16;     // heads (Dh = 64)

// Fragment layouts (1KB blocks, lane l = hf*32 + ln, 16B per lane):
//  Q/K frag: per (b,h): block (t, c), t = s/32 (64), c = d-chunk/16 (4).
//    lane l = hf*32 + (s%32); bytes = X[s][c*16 + hf*8 + j], j=0..7.
//    elem addr = (bh*256 + t*4 + c)*512 + l*8 + j        (131072 elems per bh)
//  V frag: per (b,h): block (tau, mt, c), tau = s/64 (32), mt = d/32 (2),
//    c = s-chunk-in-tile/16 (4). lane l = hf*32 + (d%32);
//    bytes = V^T[d][tau*64 + c*16 + hf*8 + j].
//    elem addr = (bh*256 + tau*8 + mt*4 + c)*512 + l*8 + j

// async global->LDS, 16B per lane; LDS dst = uniform base + lane*16 (m97 path)
__device__ __forceinline__ void gload16(const void* g, void* l) {
  __builtin_amdgcn_global_load_lds(
      (__attribute__((address_space(1))) void*)(uintptr_t)g,
      (__attribute__((address_space(3))) void*)(uint32_t)(uintptr_t)l, 16, 0, 0);
}

__device__ __forceinline__ f32x4 mfma16(bf16x8 a, bf16x8 b, f32x4 c) {
  return __builtin_amdgcn_mfma_f32_16x16x32_bf16(a, b, c, 0, 0, 0);
}
__device__ __forceinline__ f32x16 mfma32(bf16x8 a, bf16x8 b, f32x16 c) {
  return __builtin_amdgcn_mfma_f32_32x32x16_bf16(a, b, c, 0, 0, 0);
}

// ---------------------------------------------------------------------------
// cast x (fp32) -> bf16, 8 elems/thread
// ---------------------------------------------------------------------------
__global__ __launch_bounds__(256) void cast_x(const float* __restrict__ x,
                                              bf16* __restrict__ o) {
  const size_t i = ((size_t)blockIdx.x * 256 + threadIdx.x) * 8;
  const float4 a = *(const float4*)(x + i);
  const float4 b = *(const float4*)(x + i + 4);
  bf16x8 r;
  r[0] = (bf16)a.x; r[1] = (bf16)a.y; r[2] = (bf16)a.z; r[3] = (bf16)a.w;
  r[4] = (bf16)b.x; r[5] = (bf16)b.y; r[6] = (bf16)b.z; r[7] = (bf16)b.w;
  *(bf16x8*)(o + i) = r;
}

// ---------------------------------------------------------------------------
// W[k][n] fp32 -> Wt[n][k] bf16 (all 4 weight matrices, blockIdx.z selects)
// ---------------------------------------------------------------------------
__global__ __launch_bounds__(256) void transpose_cast_w(
    const float* __restrict__ W0, const float* __restrict__ W1,
    const float* __restrict__ W2, const float* __restrict__ W3,
    bf16* __restrict__ T0, bf16* __restrict__ T1, bf16* __restrict__ T2,
    bf16* __restrict__ T3) {
  const float* W;
  bf16* T;
  switch (blockIdx.z) {
    case 0: W = W0; T = T0; break;
    case 1: W = W1; T = T1; break;
    case 2: W = W2; T = T2; break;
    default: W = W3; T = T3; break;
  }
  __shared__ float t[64][65];
  const int k0 = blockIdx.y * 64, n0 = blockIdx.x * 64;
  const int tr = threadIdx.x >> 4;          // 0..15
  const int tc = (threadIdx.x & 15) * 4;    // 0..60
#pragma unroll
  for (int u = 0; u < 4; ++u) {
    const float4 v = *(const float4*)(W + (size_t)(k0 + tr + u * 16) * E + n0 + tc);
    t[tr + u * 16][tc + 0] = v.x;
    t[tr + u * 16][tc + 1] = v.y;
    t[tr + u * 16][tc + 2] = v.z;
    t[tr + u * 16][tc + 3] = v.w;
  }
  __syncthreads();
#pragma unroll
  for (int u = 0; u < 4; ++u) {
    const int n = tr + u * 16;
    bf16x4 o;
#pragma unroll
    for (int i = 0; i < 4; ++i) o[i] = (bf16)t[tc + i][n];
    *(bf16x4*)(T + (size_t)(n0 + n) * E + k0 + tc) = o;
  }
}

// ---------------------------------------------------------------------------
// Fused QKV GEMM -> MFMA-frag-layout outputs. z selects {Wq->Qf, Wk->Kf,
// Wv->Vf}. 128x128 tile, BK=32, m97 staging. z==0 scales by 0.125.
// Grid (8, 32, 3) = 768 blocks = 3/CU.
// ---------------------------------------------------------------------------
__global__ __launch_bounds__(256) void gemm_qkv(const bf16* __restrict__ A,
                                                const bf16* __restrict__ Wt,
                                                const float* __restrict__ bq,
                                                const float* __restrict__ bk,
                                                const float* __restrict__ bv,
                                                bf16* __restrict__ qo,
                                                bf16* __restrict__ ko,
                                                bf16* __restrict__ vo) {
  __shared__ __attribute__((aligned(16))) bf16 Asm[128 * 32];
  __shared__ __attribute__((aligned(16))) bf16 Bsm[128 * 32];
  const int z = blockIdx.z;
  const bf16* Bt = Wt + (size_t)z * E * E;
  const float* bias = (z == 0) ? bq : (z == 1) ? bk : bv;
  const int tid = threadIdx.x;
  const int w = tid >> 6, lane = tid & 63, quad = lane >> 4, ln = lane & 15;
  const int bm = blockIdx.y * 128, bn = blockIdx.x * 128;
  const int wr = w >> 1, wc = w & 1;
  const int srow = w * 32 + (lane >> 2);
  const int scol = (lane & 3) * 8;
  const bf16* Ag = A + (size_t)(bm + srow) * E + scol;
  const bf16* Bg = Bt + (size_t)(bn + srow) * E + scol;
  f32x4 acc[4][4] = {};

  for (int k0 = 0; k0 < E; k0 += 32) {
    gload16(Ag + k0, &Asm[(w * 32) * 32]);
    gload16(Ag + k0 + (size_t)16 * E, &Asm[(w * 32 + 16) * 32]);
    gload16(Bg + k0, &Bsm[(w * 32) * 32]);
    gload16(Bg + k0 + (size_t)16 * E, &Bsm[(w * 32 + 16) * 32]);
    __syncthreads();
    bf16x8 af[4], bfr[4];
#pragma unroll
    for (int t = 0; t < 4; ++t) {
      af[t] = *(const bf16x8*)&Asm[(wr * 64 + t * 16 + ln) * 32 + quad * 8];
      bfr[t] = *(const bf16x8*)&Bsm[(wc * 64 + t * 16 + ln) * 32 + quad * 8];
    }
#pragma unroll
    for (int rt = 0; rt < 4; ++rt)
#pragma unroll
      for (int ct = 0; ct < 4; ++ct)
        acc[rt][ct] = mfma16(af[rt], bfr[ct], acc[rt][ct]);
    __syncthreads();
  }

  const float scl = (z == 0) ? 0.125f : 1.0f;
  const int hglob = (bn + wc * 64) >> 6;  // head (wave col-group = one head)
  float bvv[4];
#pragma unroll
  for (int ct = 0; ct < 4; ++ct) bvv[ct] = bias[bn + wc * 64 + ct * 16 + ln];

#pragma unroll
  for (int rt = 0; rt < 4; ++rt) {
    const int row0 = bm + wr * 64 + rt * 16 + quad * 4;
    const int bb = row0 >> 11;        // batch (tiles never span: 2048%128==0)
    const int rl = row0 & 2047;       // seq within batch
    const size_t hb = (size_t)(bb * 16 + hglob) * 131072;
#pragma unroll
    for (int ct = 0; ct < 4; ++ct) {
      if (z == 2) {
        // V frag: d = ct*16+ln -> mt = ct>>1, ln32 = (ct&1)*16+ln;
        // s = row0 -> tau = rl>>6, hf = (rl>>3)&1, j0 = rl&7 (r gives j0..j0+3)
        const int mt = ct >> 1, ln32 = ((ct & 1) << 4) | ln;
        const int tau = rl >> 6, hfv = (rl >> 3) & 1, j0 = rl & 7;
        bf16x4 p;
#pragma unroll
        for (int r = 0; r < 4; ++r) p[r] = (bf16)(acc[rt][ct][r] + bvv[ct]);
        *(bf16x4*)&vo[hb + (size_t)((tau * 8 + mt * 4 + rt) * 512 +
                                    hfv * 256 + ln32 * 8 + j0)] = p;
      } else {
        // Q/K frag: s -> t = rl>>5, ln0 = rl&31 (+r); d = ct*16+ln ->
        // c = ct, hf = ln>>3, j = ln&7
        bf16* o = (z == 0) ? qo : ko;
        const int t = rl >> 5, ln0 = rl & 31;
        const size_t base =
            hb + (size_t)((t * 4 + ct) * 512 + (ln >> 3) * 256 + (ln & 7));
#pragma unroll
        for (int r = 0; r < 4; ++r)
          o[base + (ln0 + r) * 8] = (bf16)((acc[rt][ct][r] + bvv[ct]) * scl);
      }
    }
  }
}

// ---------------------------------------------------------------------------
// Output GEMM: C[4096][1024] fp32 = A @ Wt^T + bias. 64x128 tile -> 512 blocks.
// ---------------------------------------------------------------------------
__global__ __launch_bounds__(256) void gemm_wo(const bf16* __restrict__ A,
                                               const bf16* __restrict__ Bt,
                                               const float* __restrict__ bias,
                                               float* __restrict__ C) {
  __shared__ __attribute__((aligned(16))) bf16 Asm[64 * 32];
  __shared__ __attribute__((aligned(16))) bf16 Bsm[128 * 32];
  const int tid = threadIdx.x;
  const int w = tid >> 6, lane = tid & 63, quad = lane >> 4, ln = lane & 15;
  const int bm = blockIdx.y * 64, bn = blockIdx.x * 128;
  const int wr = w >> 1, wc = w & 1;
  const int sr = lane >> 2, sc = (lane & 3) * 8;
  const bf16* Ag = A + (size_t)(bm + w * 16 + sr) * E + sc;
  const bf16* Bg = Bt + (size_t)(bn + w * 32 + sr) * E + sc;
  f32x4 acc[2][4] = {};

  for (int k0 = 0; k0 < E; k0 += 32) {
    gload16(Ag + k0, &Asm[(w * 16) * 32]);
    gload16(Bg + k0, &Bsm[(w * 32) * 32]);
    gload16(Bg + k0 + (size_t)16 * E, &Bsm[(w * 32 + 16) * 32]);
    __syncthreads();
    bf16x8 af[2], bfr[4];
#pragma unroll
    for (int t = 0; t < 2; ++t)
      af[t] = *(const bf16x8*)&Asm[(wr * 32 + t * 16 + ln) * 32 + quad * 8];
#pragma unroll
    for (int t = 0; t < 4; ++t)
      bfr[t] = *(const bf16x8*)&Bsm[(wc * 64 + t * 16 + ln) * 32 + quad * 8];
#pragma unroll
    for (int rt = 0; rt < 2; ++rt)
#pragma unroll
      for (int ct = 0; ct < 4; ++ct)
        acc[rt][ct] = mfma16(af[rt], bfr[ct], acc[rt][ct]);
    __syncthreads();
  }

  float bvv[4];
#pragma unroll
  for (int ct = 0; ct < 4; ++ct) bvv[ct] = bias[bn + wc * 64 + ct * 16 + ln];
#pragma unroll
  for (int rt = 0; rt < 2; ++rt) {
    const int row0 = bm + wr * 32 + rt * 16 + quad * 4;
#pragma unroll
    for (int ct = 0; ct < 4; ++ct) {
      const int c = bn + wc * 64 + ct * 16 + ln;
#pragma unroll
      for (int r = 0; r < 4; ++r)
        C[(size_t)(row0 + r) * E + c] = acc[rt][ct][r] + bvv[ct];
    }
  }
}

// ---------------------------------------------------------------------------
// MFMA flash attention v3: barrier-free, frag-direct.
// One WAVE per block (64 thr), 32 q-rows; grid (S/32, H, B) = 2048 blocks.
// All Q/K/V fragments loaded straight from global in frag order (1KB
// coalesced, L2-hot). No staging LDS, no __syncthreads. LDS only holds the
// wave-private P C->A-layout round-trip (Pl, 4.7KB -> ~12 blocks/CU).
//   S^T = K.Q^T  (A = K frags, B = Q frags; C rows = kv, cols = q)
//   O^T = V^T.P^T (A = V frags, B = Pl rows)
// Deferred softmax (Q pre-scaled 1/8): scalar lpart, one shfl_xor(32) at end.
// Pl stride 74 elems -> dword stride 37 (coprime 32): conflict-free.
// ---------------------------------------------------------------------------
__global__ __launch_bounds__(64) void attn_mfma(const bf16* __restrict__ Qf,
                                                const bf16* __restrict__ Kf,
                                                const bf16* __restrict__ Vf,
                                                bf16* __restrict__ Og) {
  __shared__ __attribute__((aligned(16))) bf16 Pl[32][74];
  const int lane = threadIdx.x;
  const int ln = lane & 31, hf = lane >> 5;
  const int tq = blockIdx.x, h = blockIdx.y, b = blockIdx.z;
  const int bh = b * H + h;
  const size_t fb = (size_t)bh * 131072;  // frag base (elems) for this (b,h)

  // Q B-frags: block (tq, c), once.
  bf16x8 qf[4];
  {
    const bf16* qb = Qf + fb + (size_t)tq * 2048 + lane * 8;
#pragma unroll
    for (int c = 0; c < 4; ++c) qf[c] = *(const bf16x8*)(qb + c * 512);
  }

  const bf16* Kb = Kf + fb + lane * 8;
  const bf16* Vb = Vf + fb + lane * 8;

  float lpart = 0.f;
  f32x16 oacc[2] = {};

  for (int kt2 = 0; kt2 < S / 32; kt2 += 2) {  // 64-kv tile = 2 s-subtiles
    // scores S^T: st[mt] = K[kt2+mt] . Q^T  (A-frags direct from global)
    f32x16 st[2];
#pragma unroll
    for (int mt = 0; mt < 2; ++mt) {
      const bf16* kb2 = Kb + (size_t)(kt2 + mt) * 2048;
      f32x16 zz = {};
#pragma unroll
      for (int c = 0; c < 4; ++c)
        zz = mfma32(*(const bf16x8*)(kb2 + c * 512), qf[c], zz);
      st[mt] = zz;
    }

    // V A-frags issued early: latency hides under exp/P-write
    bf16x8 va[2][4];
    {
      const bf16* vb2 = Vb + (size_t)(kt2 >> 1) * 4096;
#pragma unroll
      for (int mt = 0; mt < 2; ++mt)
#pragma unroll
        for (int c = 0; c < 4; ++c)
          va[mt][c] = *(const bf16x8*)(vb2 + (mt * 4 + c) * 512);
    }

    // deferred softmax: exp only; P^T -> Pl[q][kv] bf16x4 b64 writes.
    // C-layout kv = (reg&3) + 8*(reg>>2) + 4*hf (+32mt)
#pragma unroll
    for (int mt = 0; mt < 2; ++mt) {
#pragma unroll
      for (int g = 0; g < 4; ++g) {
        bf16x4 pk;
#pragma unroll
        for (int j = 0; j < 4; ++j) {
          const float p = __expf(st[mt][g * 4 + j]);
          lpart += p;
          pk[j] = (bf16)p;
        }
        *(bf16x4*)&Pl[ln][mt * 32 + g * 8 + hf * 4] = pk;
      }
    }
    asm volatile("s_waitcnt lgkmcnt(0)" ::: "memory");  // wave-private drain

    // O^T += V^T . P^T
    bf16x8 pb[4];
#pragma unroll
    for (int c = 0; c < 4; ++c)
      pb[c] = *(const bf16x8*)&Pl[ln][c * 16 + hf * 8];
#pragma unroll
    for (int mt = 0; mt < 2; ++mt)
#pragma unroll
      for (int c = 0; c < 4; ++c)
        oacc[mt] = mfma32(va[mt][c], pb[c], oacc[mt]);
  }

  // the two lane-halves hold disjoint kv subsets of the same q
  lpart += __shfl_xor(lpart, 32);
  const float inv = 1.0f / lpart;

  // O^T C-layout: q = ln, d = 32mt + 8g + 4hf + j; Og row-major [s][E]
  bf16* orow = Og + ((size_t)b * S + (size_t)tq * 32 + ln) * E + h * 64;
#pragma unroll
  for (int mt = 0; mt < 2; ++mt) {
#pragma unroll
    for (int g = 0; g < 4; ++g) {
      bf16x4 o;
#pragma unroll
      for (int j = 0; j < 4; ++j) o[j] = (bf16)(oacc[mt][g * 4 + j] * inv);
      *(bf16x4*)&orow[mt * 32 + g * 8 + hf * 4] = o;
    }
  }
}

// ---------------------------------------------------------------------------
extern "C" void kernel_launch(void* const* d_in, const int* in_sizes, int n_in,
                              void* d_out, int out_size, void* d_ws, size_t ws_size,
                              hipStream_t stream) {
  const float* x = (const float*)d_in[0];
  const float* Wq = (const float*)d_in[1];
  const float* bq = (const float*)d_in[2];
  const float* Wk = (const float*)d_in[3];
  const float* bk = (const float*)d_in[4];
  const float* Wv = (const float*)d_in[5];
  const float* bv = (const float*)d_in[6];
  const float* Wo = (const float*)d_in[7];
  const float* bo = (const float*)d_in[8];

  const size_t ME = (size_t)4096 * 1024;  // 4M elems
  const size_t WE = (size_t)1024 * 1024;  // 1M elems
  bf16* xb = (bf16*)d_ws;
  bf16* wqt = xb + ME;
  bf16* wkt = wqt + WE;
  bf16* wvt = wkt + WE;
  bf16* wot = wvt + WE;
  bf16* qb = wot + WE;   // Q frags
  bf16* kb = qb + ME;    // K frags
  bf16* vt = kb + ME;    // V frags
  bf16* ab = vt + ME;    // attn out, row-major [B*S][E]

  cast_x<<<2048, 256, 0, stream>>>(x, xb);
  transpose_cast_w<<<dim3(16, 16, 4), 256, 0, stream>>>(Wq, Wk, Wv, Wo, wqt, wkt,
                                                        wvt, wot);
  gemm_qkv<<<dim3(8, 32, 3), 256, 0, stream>>>(xb, wqt, bq, bk, bv, qb, kb, vt);
  attn_mfma<<<dim3(S / 32, H, 2), 64, 0, stream>>>(qb, kb, vt, ab);
  gemm_wo<<<dim3(8, 64), 256, 0, stream>>>(ab, wot, bo, (float*)d_out);
}

// Round 6
// 202.980 us; speedup vs baseline: 1.0061x; 1.0061x over previous
//
#include <hip/hip_runtime.h>
#include <math.h>
#include <stdint.h>

typedef __bf16 bf16;
typedef __bf16 bf16x4 __attribute__((ext_vector_type(4)));
typedef __bf16 bf16x8 __attribute__((ext_vector_type(8)));
typedef float f32x4 __attribute__((ext_vector_type(4)));
typedef float f32x16 __attribute__((ext_vector_type(16)));

constexpr int E = 1024;   // embed dim
constexpr int S = 2048;   // seq len
constexpr int H = 16;     // heads (Dh = 64)

// Fragment layouts (1KB blocks, lane l = hf*32 + ln, 16B per lane):
//  Q/K frag: per (b,h): block (t, c), t = s/32 (64), c = d-chunk/16 (4).
//    lane l = hf*32 + (s%32); bytes = X[s][c*16 + hf*8 + j], j=0..7.
//    elem addr = (bh*256 + t*4 + c)*512 + l*8 + j        (131072 elems per bh)
//  V frag: per (b,h): block (tau, mt, c), tau = s/64 (32), mt = d/32 (2),
//    c = s-chunk-in-tile/16 (4). lane l = hf*32 + (d%32);
//    bytes = V^T[d][tau*64 + c*16 + hf*8 + j].
//    elem addr = (bh*256 + tau*8 + mt*4 + c)*512 + l*8 + j

// async global->LDS, 16B per lane; LDS dst = uniform base + lane*16 (m97 path)
__device__ __forceinline__ void gload16(const void* g, void* l) {
  __builtin_amdgcn_global_load_lds(
      (__attribute__((address_space(1))) void*)(uintptr_t)g,
      (__attribute__((address_space(3))) void*)(uint32_t)(uintptr_t)l, 16, 0, 0);
}

__device__ __forceinline__ f32x4 mfma16(bf16x8 a, bf16x8 b, f32x4 c) {
  return __builtin_amdgcn_mfma_f32_16x16x32_bf16(a, b, c, 0, 0, 0);
}
__device__ __forceinline__ f32x16 mfma32(bf16x8 a, bf16x8 b, f32x16 c) {
  return __builtin_amdgcn_mfma_f32_32x32x16_bf16(a, b, c, 0, 0, 0);
}

// ---------------------------------------------------------------------------
// cast x (fp32) -> bf16, 8 elems/thread
// ---------------------------------------------------------------------------
__global__ __launch_bounds__(256) void cast_x(const float* __restrict__ x,
                                              bf16* __restrict__ o) {
  const size_t i = ((size_t)blockIdx.x * 256 + threadIdx.x) * 8;
  const float4 a = *(const float4*)(x + i);
  const float4 b = *(const float4*)(x + i + 4);
  bf16x8 r;
  r[0] = (bf16)a.x; r[1] = (bf16)a.y; r[2] = (bf16)a.z; r[3] = (bf16)a.w;
  r[4] = (bf16)b.x; r[5] = (bf16)b.y; r[6] = (bf16)b.z; r[7] = (bf16)b.w;
  *(bf16x8*)(o + i) = r;
}

// ---------------------------------------------------------------------------
// W[k][n] fp32 -> Wt[n][k] bf16 (all 4 weight matrices, blockIdx.z selects)
// ---------------------------------------------------------------------------
__global__ __launch_bounds__(256) void transpose_cast_w(
    const float* __restrict__ W0, const float* __restrict__ W1,
    const float* __restrict__ W2, const float* __restrict__ W3,
    bf16* __restrict__ T0, bf16* __restrict__ T1, bf16* __restrict__ T2,
    bf16* __restrict__ T3) {
  const float* W;
  bf16* T;
  switch (blockIdx.z) {
    case 0: W = W0; T = T0; break;
    case 1: W = W1; T = T1; break;
    case 2: W = W2; T = T2; break;
    default: W = W3; T = T3; break;
  }
  __shared__ float t[64][65];
  const int k0 = blockIdx.y * 64, n0 = blockIdx.x * 64;
  const int tr = threadIdx.x >> 4;          // 0..15
  const int tc = (threadIdx.x & 15) * 4;    // 0..60
#pragma unroll
  for (int u = 0; u < 4; ++u) {
    const float4 v = *(const float4*)(W + (size_t)(k0 + tr + u * 16) * E + n0 + tc);
    t[tr + u * 16][tc + 0] = v.x;
    t[tr + u * 16][tc + 1] = v.y;
    t[tr + u * 16][tc + 2] = v.z;
    t[tr + u * 16][tc + 3] = v.w;
  }
  __syncthreads();
#pragma unroll
  for (int u = 0; u < 4; ++u) {
    const int n = tr + u * 16;
    bf16x4 o;
#pragma unroll
    for (int i = 0; i < 4; ++i) o[i] = (bf16)t[tc + i][n];
    *(bf16x4*)(T + (size_t)(n0 + n) * E + k0 + tc) = o;
  }
}

// ---------------------------------------------------------------------------
// Fused QKV GEMM -> MFMA-frag-layout outputs. z selects {Wq->Qf, Wk->Kf,
// Wv->Vf}. 128x128 tile, BK=32, m97 staging. z==0 scales by 0.125.
// Grid (8, 32, 3) = 768 blocks = 3/CU.
// ---------------------------------------------------------------------------
__global__ __launch_bounds__(256) void gemm_qkv(const bf16* __restrict__ A,
                                                const bf16* __restrict__ Wt,
                                                const float* __restrict__ bq,
                                                const float* __restrict__ bk,
                                                const float* __restrict__ bv,
                                                bf16* __restrict__ qo,
                                                bf16* __restrict__ ko,
                                                bf16* __restrict__ vo) {
  __shared__ __attribute__((aligned(16))) bf16 Asm[128 * 32];
  __shared__ __attribute__((aligned(16))) bf16 Bsm[128 * 32];
  const int z = blockIdx.z;
  const bf16* Bt = Wt + (size_t)z * E * E;
  const float* bias = (z == 0) ? bq : (z == 1) ? bk : bv;
  const int tid = threadIdx.x;
  const int w = tid >> 6, lane = tid & 63, quad = lane >> 4, ln = lane & 15;
  const int bm = blockIdx.y * 128, bn = blockIdx.x * 128;
  const int wr = w >> 1, wc = w & 1;
  const int srow = w * 32 + (lane >> 2);
  const int scol = (lane & 3) * 8;
  const bf16* Ag = A + (size_t)(bm + srow) * E + scol;
  const bf16* Bg = Bt + (size_t)(bn + srow) * E + scol;
  f32x4 acc[4][4] = {};

  for (int k0 = 0; k0 < E; k0 += 32) {
    gload16(Ag + k0, &Asm[(w * 32) * 32]);
    gload16(Ag + k0 + (size_t)16 * E, &Asm[(w * 32 + 16) * 32]);
    gload16(Bg + k0, &Bsm[(w * 32) * 32]);
    gload16(Bg + k0 + (size_t)16 * E, &Bsm[(w * 32 + 16) * 32]);
    __syncthreads();
    bf16x8 af[4], bfr[4];
#pragma unroll
    for (int t = 0; t < 4; ++t) {
      af[t] = *(const bf16x8*)&Asm[(wr * 64 + t * 16 + ln) * 32 + quad * 8];
      bfr[t] = *(const bf16x8*)&Bsm[(wc * 64 + t * 16 + ln) * 32 + quad * 8];
    }
#pragma unroll
    for (int rt = 0; rt < 4; ++rt)
#pragma unroll
      for (int ct = 0; ct < 4; ++ct)
        acc[rt][ct] = mfma16(af[rt], bfr[ct], acc[rt][ct]);
    __syncthreads();
  }

  const float scl = (z == 0) ? 0.125f : 1.0f;
  const int hglob = (bn + wc * 64) >> 6;  // head (wave col-group = one head)
  float bvv[4];
#pragma unroll
  for (int ct = 0; ct < 4; ++ct) bvv[ct] = bias[bn + wc * 64 + ct * 16 + ln];

#pragma unroll
  for (int rt = 0; rt < 4; ++rt) {
    const int row0 = bm + wr * 64 + rt * 16 + quad * 4;
    const int bb = row0 >> 11;        // batch (tiles never span: 2048%128==0)
    const int rl = row0 & 2047;       // seq within batch
    const size_t hb = (size_t)(bb * 16 + hglob) * 131072;
#pragma unroll
    for (int ct = 0; ct < 4; ++ct) {
      if (z == 2) {
        // V frag: d = ct*16+ln -> mt = ct>>1, ln32 = (ct&1)*16+ln;
        // s = row0 -> tau = rl>>6, hf = (rl>>3)&1, j0 = rl&7 (r gives j0..j0+3)
        const int mt = ct >> 1, ln32 = ((ct & 1) << 4) | ln;
        const int tau = rl >> 6, hfv = (rl >> 3) & 1, j0 = rl & 7;
        bf16x4 p;
#pragma unroll
        for (int r = 0; r < 4; ++r) p[r] = (bf16)(acc[rt][ct][r] + bvv[ct]);
        *(bf16x4*)&vo[hb + (size_t)((tau * 8 + mt * 4 + rt) * 512 +
                                    hfv * 256 + ln32 * 8 + j0)] = p;
      } else {
        // Q/K frag: s -> t = rl>>5, ln0 = rl&31 (+r); d = ct*16+ln ->
        // c = ct, hf = ln>>3, j = ln&7
        bf16* o = (z == 0) ? qo : ko;
        const int t = rl >> 5, ln0 = rl & 31;
        const size_t base =
            hb + (size_t)((t * 4 + ct) * 512 + (ln >> 3) * 256 + (ln & 7));
#pragma unroll
        for (int r = 0; r < 4; ++r)
          o[base + (ln0 + r) * 8] = (bf16)((acc[rt][ct][r] + bvv[ct]) * scl);
      }
    }
  }
}

// ---------------------------------------------------------------------------
// Output GEMM: C[4096][1024] fp32 = A @ Wt^T + bias. 64x128 tile -> 512 blocks.
// ---------------------------------------------------------------------------
__global__ __launch_bounds__(256) void gemm_wo(const bf16* __restrict__ A,
                                               const bf16* __restrict__ Bt,
                                               const float* __restrict__ bias,
                                               float* __restrict__ C) {
  __shared__ __attribute__((aligned(16))) bf16 Asm[64 * 32];
  __shared__ __attribute__((aligned(16))) bf16 Bsm[128 * 32];
  const int tid = threadIdx.x;
  const int w = tid >> 6, lane = tid & 63, quad = lane >> 4, ln = lane & 15;
  const int bm = blockIdx.y * 64, bn = blockIdx.x * 128;
  const int wr = w >> 1, wc = w & 1;
  const int sr = lane >> 2, sc = (lane & 3) * 8;
  const bf16* Ag = A + (size_t)(bm + w * 16 + sr) * E + sc;
  const bf16* Bg = Bt + (size_t)(bn + w * 32 + sr) * E + sc;
  f32x4 acc[2][4] = {};

  for (int k0 = 0; k0 < E; k0 += 32) {
    gload16(Ag + k0, &Asm[(w * 16) * 32]);
    gload16(Bg + k0, &Bsm[(w * 32) * 32]);
    gload16(Bg + k0 + (size_t)16 * E, &Bsm[(w * 32 + 16) * 32]);
    __syncthreads();
    bf16x8 af[2], bfr[4];
#pragma unroll
    for (int t = 0; t < 2; ++t)
      af[t] = *(const bf16x8*)&Asm[(wr * 32 + t * 16 + ln) * 32 + quad * 8];
#pragma unroll
    for (int t = 0; t < 4; ++t)
      bfr[t] = *(const bf16x8*)&Bsm[(wc * 64 + t * 16 + ln) * 32 + quad * 8];
#pragma unroll
    for (int rt = 0; rt < 2; ++rt)
#pragma unroll
      for (int ct = 0; ct < 4; ++ct)
        acc[rt][ct] = mfma16(af[rt], bfr[ct], acc[rt][ct]);
    __syncthreads();
  }

  float bvv[4];
#pragma unroll
  for (int ct = 0; ct < 4; ++ct) bvv[ct] = bias[bn + wc * 64 + ct * 16 + ln];
#pragma unroll
  for (int rt = 0; rt < 2; ++rt) {
    const int row0 = bm + wr * 32 + rt * 16 + quad * 4;
#pragma unroll
    for (int ct = 0; ct < 4; ++ct) {
      const int c = bn + wc * 64 + ct * 16 + ln;
#pragma unroll
      for (int r = 0; r < 4; ++r)
        C[(size_t)(row0 + r) * E + c] = acc[rt][ct][r] + bvv[ct];
    }
  }
}

// ---------------------------------------------------------------------------
// MFMA flash attention v4: barrier-free main loop + kv-split x2.
// Block = 256 thr = 4 waves = 2 q-tiles x 2 kv-halves; grid (S/64, H, B) =
// 1024 blocks = 4 blocks/CU -> 16 waves/CU (2x round-5 parallelism).
// Each wave: 32 q-rows, half the kv range, frag-direct global loads (no
// staging LDS, no barriers in the loop). Deferred softmax => partials over
// disjoint kv ranges combine by ADDITION: ki=1 waves park O/l partials in
// LDS, one __syncthreads, ki=0 waves sum + normalize + store.
// Paired q-waves (same ki) read identical K/V addresses -> L1 hits.
// LDS: Pl 18.9K + Cb 16K + Lb 0.5K = 35.8 KB -> exactly 4 blocks/CU.
// ---------------------------------------------------------------------------
__global__ __launch_bounds__(256, 4) void attn_mfma(const bf16* __restrict__ Qf,
                                                    const bf16* __restrict__ Kf,
                                                    const bf16* __restrict__ Vf,
                                                    bf16* __restrict__ Og) {
  __shared__ __attribute__((aligned(16))) bf16 Pl[4][32][74];
  __shared__ float Cb[2][32][64];  // [qi][acc elem][lane] partial O
  __shared__ float Lb[2][64];      // [qi][lane] partial l
  const int tid = threadIdx.x;
  const int lane = tid & 63, w = tid >> 6;
  const int qi = w & 1, ki = w >> 1;      // q-tile select, kv-half select
  const int ln = lane & 31, hf = lane >> 5;
  const int tq = blockIdx.x * 2 + qi, h = blockIdx.y, b = blockIdx.z;
  const size_t fb = (size_t)(b * H + h) * 131072;  // frag base for this (b,h)

  // Q B-frags: block (tq, c), once.
  bf16x8 qf[4];
  {
    const bf16* qb = Qf + fb + (size_t)tq * 2048 + lane * 8;
#pragma unroll
    for (int c = 0; c < 4; ++c) qf[c] = *(const bf16x8*)(qb + c * 512);
  }

  const bf16* Kb = Kf + fb + lane * 8;
  const bf16* Vb = Vf + fb + lane * 8;

  float lpart = 0.f;
  f32x16 oacc[2] = {};

  // kv half: 32-kv subtile units [ki*32, ki*32+32), 64-kv tiles (step 2)
  const int kt2lo = ki * (S / 64);
  for (int kt2 = kt2lo; kt2 < kt2lo + S / 64; kt2 += 2) {
    // scores S^T: st[mt] = K[kt2+mt] . Q^T  (A-frags direct from global)
    f32x16 st[2];
#pragma unroll
    for (int mt = 0; mt < 2; ++mt) {
      const bf16* kb2 = Kb + (size_t)(kt2 + mt) * 2048;
      f32x16 zz = {};
#pragma unroll
      for (int c = 0; c < 4; ++c)
        zz = mfma32(*(const bf16x8*)(kb2 + c * 512), qf[c], zz);
      st[mt] = zz;
    }

    // V A-frags issued early: latency hides under exp/P-write
    bf16x8 va[2][4];
    {
      const bf16* vb2 = Vb + (size_t)(kt2 >> 1) * 4096;
#pragma unroll
      for (int mt = 0; mt < 2; ++mt)
#pragma unroll
        for (int c = 0; c < 4; ++c)
          va[mt][c] = *(const bf16x8*)(vb2 + (mt * 4 + c) * 512);
    }

    // deferred softmax: exp only; P^T -> Pl[q][kv] bf16x4 b64 writes.
    // C-layout kv = (reg&3) + 8*(reg>>2) + 4*hf (+32mt)
#pragma unroll
    for (int mt = 0; mt < 2; ++mt) {
#pragma unroll
      for (int g = 0; g < 4; ++g) {
        bf16x4 pk;
#pragma unroll
        for (int j = 0; j < 4; ++j) {
          const float p = __expf(st[mt][g * 4 + j]);
          lpart += p;
          pk[j] = (bf16)p;
        }
        *(bf16x4*)&Pl[w][ln][mt * 32 + g * 8 + hf * 4] = pk;
      }
    }
    asm volatile("s_waitcnt lgkmcnt(0)" ::: "memory");  // wave-private drain

    // O^T += V^T . P^T
    bf16x8 pb[4];
#pragma unroll
    for (int c = 0; c < 4; ++c)
      pb[c] = *(const bf16x8*)&Pl[w][ln][c * 16 + hf * 8];
#pragma unroll
    for (int mt = 0; mt < 2; ++mt)
#pragma unroll
      for (int c = 0; c < 4; ++c)
        oacc[mt] = mfma32(va[mt][c], pb[c], oacc[mt]);
  }

  // ---- kv-half combine (partials over disjoint kv simply add) ----
  if (ki == 1) {
#pragma unroll
    for (int mt = 0; mt < 2; ++mt)
#pragma unroll
      for (int i = 0; i < 16; ++i) Cb[qi][mt * 16 + i][lane] = oacc[mt][i];
    Lb[qi][lane] = lpart;
  }
  __syncthreads();
  if (ki == 0) {
#pragma unroll
    for (int mt = 0; mt < 2; ++mt)
#pragma unroll
      for (int i = 0; i < 16; ++i) oacc[mt][i] += Cb[qi][mt * 16 + i][lane];
    lpart += Lb[qi][lane];

    // the two lane-halves hold disjoint kv subsets of the same q
    lpart += __shfl_xor(lpart, 32);
    const float inv = 1.0f / lpart;

    // O^T C-layout: q = ln, d = 32mt + 8g + 4hf + j; Og row-major [s][E]
    bf16* orow = Og + ((size_t)b * S + (size_t)tq * 32 + ln) * E + h * 64;
#pragma unroll
    for (int mt = 0; mt < 2; ++mt) {
#pragma unroll
      for (int g = 0; g < 4; ++g) {
        bf16x4 o;
#pragma unroll
        for (int j = 0; j < 4; ++j) o[j] = (bf16)(oacc[mt][g * 4 + j] * inv);
        *(bf16x4*)&orow[mt * 32 + g * 8 + hf * 4] = o;
      }
    }
  }
}

// ---------------------------------------------------------------------------
extern "C" void kernel_launch(void* const* d_in, const int* in_sizes, int n_in,
                              void* d_out, int out_size, void* d_ws, size_t ws_size,
                              hipStream_t stream) {
  const float* x = (const float*)d_in[0];
  const float* Wq = (const float*)d_in[1];
  const float* bq = (const float*)d_in[2];
  const float* Wk = (const float*)d_in[3];
  const float* bk = (const float*)d_in[4];
  const float* Wv = (const float*)d_in[5];
  const float* bv = (const float*)d_in[6];
  const float* Wo = (const float*)d_in[7];
  const float* bo = (const float*)d_in[8];

  const size_t ME = (size_t)4096 * 1024;  // 4M elems
  const size_t WE = (size_t)1024 * 1024;  // 1M elems
  bf16* xb = (bf16*)d_ws;
  bf16* wqt = xb + ME;
  bf16* wkt = wqt + WE;
  bf16* wvt = wkt + WE;
  bf16* wot = wvt + WE;
  bf16* qb = wot + WE;   // Q frags
  bf16* kb = qb + ME;    // K frags
  bf16* vt = kb + ME;    // V frags
  bf16* ab = vt + ME;    // attn out, row-major [B*S][E]

  cast_x<<<2048, 256, 0, stream>>>(x, xb);
  transpose_cast_w<<<dim3(16, 16, 4), 256, 0, stream>>>(Wq, Wk, Wv, Wo, wqt, wkt,
                                                        wvt, wot);
  gemm_qkv<<<dim3(8, 32, 3), 256, 0, stream>>>(xb, wqt, bq, bk, bv, qb, kb, vt);
  attn_mfma<<<dim3(S / 64, H, 2), 256, 0, stream>>>(qb, kb, vt, ab);
  gemm_wo<<<dim3(8, 64), 256, 0, stream>>>(ab, wot, bo, (float*)d_out);
}

// Round 7
// 191.454 us; speedup vs baseline: 1.0666x; 1.0602x over previous
//
#include <hip/hip_runtime.h>
#include <math.h>
#include <stdint.h>

typedef __bf16 bf16;
typedef __bf16 bf16x4 __attribute__((ext_vector_type(4)));
typedef __bf16 bf16x8 __attribute__((ext_vector_type(8)));
typedef float f32x4 __attribute__((ext_vector_type(4)));
typedef float f32x16 __attribute__((ext_vector_type(16)));

constexpr int E = 1024;   // embed dim
constexpr int S = 2048;   // seq len
constexpr int H = 16;     // heads (Dh = 64)

// Fragment layouts (1KB blocks, lane l = hf*32 + ln, 16B per lane):
//  Q/K frag: per (b,h): block (t, c), t = s/32 (64), c = d-chunk/16 (4).
//    lane l = hf*32 + (s%32); bytes = X[s][c*16 + hf*8 + j], j=0..7.
//    elem addr = (bh*256 + t*4 + c)*512 + l*8 + j        (131072 elems per bh)
//  V frag: per (b,h): block (tau, mt, c), tau = s/64 (32), mt = d/32 (2),
//    c = s-chunk-in-tile/16 (4). lane l = hf*32 + (d%32);
//    bytes = V^T[d][tau*64 + c*16 + hf*8 + j].
//    elem addr = (bh*256 + tau*8 + mt*4 + c)*512 + l*8 + j
//  => a 64-kv tile of K or V is elems [tau*4096, tau*4096+4096): 8KB contiguous.

// async global->LDS, 16B per lane; LDS dst = wave-uniform base + lane*16
__device__ __forceinline__ void gload16(const void* g, void* l) {
  __builtin_amdgcn_global_load_lds(
      (__attribute__((address_space(1))) void*)(uintptr_t)g,
      (__attribute__((address_space(3))) void*)(uint32_t)(uintptr_t)l, 16, 0, 0);
}

__device__ __forceinline__ f32x4 mfma16(bf16x8 a, bf16x8 b, f32x4 c) {
  return __builtin_amdgcn_mfma_f32_16x16x32_bf16(a, b, c, 0, 0, 0);
}
__device__ __forceinline__ f32x16 mfma32(bf16x8 a, bf16x8 b, f32x16 c) {
  return __builtin_amdgcn_mfma_f32_32x32x16_bf16(a, b, c, 0, 0, 0);
}
__device__ __forceinline__ void lgkm0() {
  asm volatile("s_waitcnt lgkmcnt(0)" ::: "memory");
}

// ---------------------------------------------------------------------------
// cast x (fp32) -> bf16, 8 elems/thread
// ---------------------------------------------------------------------------
__global__ __launch_bounds__(256) void cast_x(const float* __restrict__ x,
                                              bf16* __restrict__ o) {
  const size_t i = ((size_t)blockIdx.x * 256 + threadIdx.x) * 8;
  const float4 a = *(const float4*)(x + i);
  const float4 b = *(const float4*)(x + i + 4);
  bf16x8 r;
  r[0] = (bf16)a.x; r[1] = (bf16)a.y; r[2] = (bf16)a.z; r[3] = (bf16)a.w;
  r[4] = (bf16)b.x; r[5] = (bf16)b.y; r[6] = (bf16)b.z; r[7] = (bf16)b.w;
  *(bf16x8*)(o + i) = r;
}

// ---------------------------------------------------------------------------
// W[k][n] fp32 -> Wt[n][k] bf16 (all 4 weight matrices, blockIdx.z selects)
// ---------------------------------------------------------------------------
__global__ __launch_bounds__(256) void transpose_cast_w(
    const float* __restrict__ W0, const float* __restrict__ W1,
    const float* __restrict__ W2, const float* __restrict__ W3,
    bf16* __restrict__ T0, bf16* __restrict__ T1, bf16* __restrict__ T2,
    bf16* __restrict__ T3) {
  const float* W;
  bf16* T;
  switch (blockIdx.z) {
    case 0: W = W0; T = T0; break;
    case 1: W = W1; T = T1; break;
    case 2: W = W2; T = T2; break;
    default: W = W3; T = T3; break;
  }
  __shared__ float t[64][65];
  const int k0 = blockIdx.y * 64, n0 = blockIdx.x * 64;
  const int tr = threadIdx.x >> 4;          // 0..15
  const int tc = (threadIdx.x & 15) * 4;    // 0..60
#pragma unroll
  for (int u = 0; u < 4; ++u) {
    const float4 v = *(const float4*)(W + (size_t)(k0 + tr + u * 16) * E + n0 + tc);
    t[tr + u * 16][tc + 0] = v.x;
    t[tr + u * 16][tc + 1] = v.y;
    t[tr + u * 16][tc + 2] = v.z;
    t[tr + u * 16][tc + 3] = v.w;
  }
  __syncthreads();
#pragma unroll
  for (int u = 0; u < 4; ++u) {
    const int n = tr + u * 16;
    bf16x4 o;
#pragma unroll
    for (int i = 0; i < 4; ++i) o[i] = (bf16)t[tc + i][n];
    *(bf16x4*)(T + (size_t)(n0 + n) * E + k0 + tc) = o;
  }
}

// ---------------------------------------------------------------------------
// Fused QKV GEMM -> MFMA-frag-layout outputs. z selects {Wq->Qf, Wk->Kf,
// Wv->Vf}. 128x128 tile, BK=32, m97 staging. z==0 scales by 0.125.
// Grid (8, 32, 3) = 768 blocks = 3/CU.
// ---------------------------------------------------------------------------
__global__ __launch_bounds__(256) void gemm_qkv(const bf16* __restrict__ A,
                                                const bf16* __restrict__ Wt,
                                                const float* __restrict__ bq,
                                                const float* __restrict__ bk,
                                                const float* __restrict__ bv,
                                                bf16* __restrict__ qo,
                                                bf16* __restrict__ ko,
                                                bf16* __restrict__ vo) {
  __shared__ __attribute__((aligned(16))) bf16 Asm[128 * 32];
  __shared__ __attribute__((aligned(16))) bf16 Bsm[128 * 32];
  const int z = blockIdx.z;
  const bf16* Bt = Wt + (size_t)z * E * E;
  const float* bias = (z == 0) ? bq : (z == 1) ? bk : bv;
  const int tid = threadIdx.x;
  const int w = tid >> 6, lane = tid & 63, quad = lane >> 4, ln = lane & 15;
  const int bm = blockIdx.y * 128, bn = blockIdx.x * 128;
  const int wr = w >> 1, wc = w & 1;
  const int srow = w * 32 + (lane >> 2);
  const int scol = (lane & 3) * 8;
  const bf16* Ag = A + (size_t)(bm + srow) * E + scol;
  const bf16* Bg = Bt + (size_t)(bn + srow) * E + scol;
  f32x4 acc[4][4] = {};

  for (int k0 = 0; k0 < E; k0 += 32) {
    gload16(Ag + k0, &Asm[(w * 32) * 32]);
    gload16(Ag + k0 + (size_t)16 * E, &Asm[(w * 32 + 16) * 32]);
    gload16(Bg + k0, &Bsm[(w * 32) * 32]);
    gload16(Bg + k0 + (size_t)16 * E, &Bsm[(w * 32 + 16) * 32]);
    __syncthreads();
    bf16x8 af[4], bfr[4];
#pragma unroll
    for (int t = 0; t < 4; ++t) {
      af[t] = *(const bf16x8*)&Asm[(wr * 64 + t * 16 + ln) * 32 + quad * 8];
      bfr[t] = *(const bf16x8*)&Bsm[(wc * 64 + t * 16 + ln) * 32 + quad * 8];
    }
#pragma unroll
    for (int rt = 0; rt < 4; ++rt)
#pragma unroll
      for (int ct = 0; ct < 4; ++ct)
        acc[rt][ct] = mfma16(af[rt], bfr[ct], acc[rt][ct]);
    __syncthreads();
  }

  const float scl = (z == 0) ? 0.125f : 1.0f;
  const int hglob = (bn + wc * 64) >> 6;  // head (wave col-group = one head)
  float bvv[4];
#pragma unroll
  for (int ct = 0; ct < 4; ++ct) bvv[ct] = bias[bn + wc * 64 + ct * 16 + ln];

#pragma unroll
  for (int rt = 0; rt < 4; ++rt) {
    const int row0 = bm + wr * 64 + rt * 16 + quad * 4;
    const int bb = row0 >> 11;        // batch (tiles never span: 2048%128==0)
    const int rl = row0 & 2047;       // seq within batch
    const size_t hb = (size_t)(bb * 16 + hglob) * 131072;
#pragma unroll
    for (int ct = 0; ct < 4; ++ct) {
      if (z == 2) {
        // V frag: d = ct*16+ln -> mt = ct>>1, ln32 = (ct&1)*16+ln;
        // s = row0 -> tau = rl>>6, hf = (rl>>3)&1, j0 = rl&7 (r gives j0..j0+3)
        const int mt = ct >> 1, ln32 = ((ct & 1) << 4) | ln;
        const int tau = rl >> 6, hfv = (rl >> 3) & 1, j0 = rl & 7;
        bf16x4 p;
#pragma unroll
        for (int r = 0; r < 4; ++r) p[r] = (bf16)(acc[rt][ct][r] + bvv[ct]);
        *(bf16x4*)&vo[hb + (size_t)((tau * 8 + mt * 4 + rt) * 512 +
                                    hfv * 256 + ln32 * 8 + j0)] = p;
      } else {
        // Q/K frag: s -> t = rl>>5, ln0 = rl&31 (+r); d = ct*16+ln ->
        // c = ct, hf = ln>>3, j = ln&7
        bf16* o = (z == 0) ? qo : ko;
        const int t = rl >> 5, ln0 = rl & 31;
        const size_t base =
            hb + (size_t)((t * 4 + ct) * 512 + (ln >> 3) * 256 + (ln & 7));
#pragma unroll
        for (int r = 0; r < 4; ++r)
          o[base + (ln0 + r) * 8] = (bf16)((acc[rt][ct][r] + bvv[ct]) * scl);
      }
    }
  }
}

// ---------------------------------------------------------------------------
// Output GEMM: C[4096][1024] fp32 = A @ Wt^T + bias. 64x128 tile -> 512 blocks.
// ---------------------------------------------------------------------------
__global__ __launch_bounds__(256) void gemm_wo(const bf16* __restrict__ A,
                                               const bf16* __restrict__ Bt,
                                               const float* __restrict__ bias,
                                               float* __restrict__ C) {
  __shared__ __attribute__((aligned(16))) bf16 Asm[64 * 32];
  __shared__ __attribute__((aligned(16))) bf16 Bsm[128 * 32];
  const int tid = threadIdx.x;
  const int w = tid >> 6, lane = tid & 63, quad = lane >> 4, ln = lane & 15;
  const int bm = blockIdx.y * 64, bn = blockIdx.x * 128;
  const int wr = w >> 1, wc = w & 1;
  const int sr = lane >> 2, sc = (lane & 3) * 8;
  const bf16* Ag = A + (size_t)(bm + w * 16 + sr) * E + sc;
  const bf16* Bg = Bt + (size_t)(bn + w * 32 + sr) * E + sc;
  f32x4 acc[2][4] = {};

  for (int k0 = 0; k0 < E; k0 += 32) {
    gload16(Ag + k0, &Asm[(w * 16) * 32]);
    gload16(Bg + k0, &Bsm[(w * 32) * 32]);
    gload16(Bg + k0 + (size_t)16 * E, &Bsm[(w * 32 + 16) * 32]);
    __syncthreads();
    bf16x8 af[2], bfr[4];
#pragma unroll
    for (int t = 0; t < 2; ++t)
      af[t] = *(const bf16x8*)&Asm[(wr * 32 + t * 16 + ln) * 32 + quad * 8];
#pragma unroll
    for (int t = 0; t < 4; ++t)
      bfr[t] = *(const bf16x8*)&Bsm[(wc * 64 + t * 16 + ln) * 32 + quad * 8];
#pragma unroll
    for (int rt = 0; rt < 2; ++rt)
#pragma unroll
      for (int ct = 0; ct < 4; ++ct)
        acc[rt][ct] = mfma16(af[rt], bfr[ct], acc[rt][ct]);
    __syncthreads();
  }

  float bvv[4];
#pragma unroll
  for (int ct = 0; ct < 4; ++ct) bvv[ct] = bias[bn + wc * 64 + ct * 16 + ln];
#pragma unroll
  for (int rt = 0; rt < 2; ++rt) {
    const int row0 = bm + wr * 32 + rt * 16 + quad * 4;
#pragma unroll
    for (int ct = 0; ct < 4; ++ct) {
      const int c = bn + wc * 64 + ct * 16 + ln;
#pragma unroll
      for (int r = 0; r < 4; ++r)
        C[(size_t)(row0 + r) * E + c] = acc[rt][ct][r] + bvv[ct];
    }
  }
}

// ---------------------------------------------------------------------------
// MFMA flash attention v6: LDS-shared K/V (4x L2-traffic cut = the measured
// 16 TB/s bottleneck), frag-layout staging via global_load_lds.
// Block = 512 thr = 8 waves = 4 q-tiles x 2 kv-halves; grid (S/128, H, B) =
// 512 blocks = 2 blocks/CU = 16 waves/CU.
// Per 64-kv tile: each kv-half group stages its 8KB K-tile + 8KB V-tile
// (contiguous frag blocks; LDS copy is operand-ready, conflict-free b128
// reads at uniform-base + lane*16). m97-style 2-barrier loop.
// P round-trip: frag-block layout per mt-half (2KB/wave, reused across mt
// with lgkm guards). Deferred softmax; in-block additive kv combine.
// LDS: K 16K + V 16K + P 16K = 48 KB.
// ---------------------------------------------------------------------------
__global__ __launch_bounds__(512, 4) void attn_mfma(const bf16* __restrict__ Qf,
                                                    const bf16* __restrict__ Kf,
                                                    const bf16* __restrict__ Vf,
                                                    bf16* __restrict__ Og) {
  __shared__ __attribute__((aligned(16))) char smem[49152];
  bf16* KsB = (bf16*)smem;                  // [ki][4096]  (2 x 8 KB)
  bf16* VsB = (bf16*)(smem + 16384);        // [ki][4096]
  bf16* PlB = (bf16*)(smem + 32768);        // [wave][1024] (8 x 2 KB)

  const int tid = threadIdx.x;
  const int w = tid >> 6, lane = tid & 63, ln = lane & 31, hf = lane >> 5;
  const int qi = w & 3, ki = w >> 2;
  const int tq = blockIdx.x * 4 + qi;       // q-tile (32 q-rows)
  const int h = blockIdx.y, b = blockIdx.z;
  const size_t fb = (size_t)(b * H + h) * 131072;

  // Q B-frags once (B[k=d][n=q]): lane q = ln, d = c*16 + hf*8 + j
  bf16x8 qf[4];
  {
    const bf16* qb = Qf + fb + (size_t)tq * 2048 + lane * 8;
#pragma unroll
    for (int c = 0; c < 4; ++c) qf[c] = *(const bf16x8*)(qb + c * 512);
  }

  bf16* Ks = KsB + ki * 4096;
  bf16* Vs = VsB + ki * 4096;
  bf16* Pw = PlB + w * 1024;

  // staging: wave (qi,ki) copies chunks qi*2, qi*2+1 of its group's tile
  const bf16* Ksrc = Kf + fb + qi * 1024 + lane * 8;
  const bf16* Vsrc = Vf + fb + qi * 1024 + lane * 8;
  bf16* Kdst = Ks + qi * 1024;   // wave-uniform base (+512 for 2nd chunk)
  bf16* Vdst = Vs + qi * 1024;

  float lpart = 0.f;
  f32x16 oacc[2] = {};

  for (int i = 0; i < 16; ++i) {
    const size_t toff = (size_t)(ki * 16 + i) * 4096;  // this group's tile
    gload16(Ksrc + toff, Kdst);
    gload16(Ksrc + toff + 512, Kdst + 512);
    gload16(Vsrc + toff, Vdst);
    gload16(Vsrc + toff + 512, Vdst + 512);
    __syncthreads();  // vmcnt(0) drained: all 8 waves' tiles staged

#pragma unroll
    for (int mt = 0; mt < 2; ++mt) {
      // scores S^T (rows kv, cols q): A = K frags, B = qf
      f32x16 st = {};
#pragma unroll
      for (int c = 0; c < 4; ++c)
        st = mfma32(*(const bf16x8*)&Ks[(mt * 4 + c) * 512 + lane * 8], qf[c], st);

      // deferred softmax: exp only; P -> frag-block layout in Pw.
      // C-layout kv_local = (reg&3) + 8*(reg>>2) + 4*hf; dest elem =
      // g*256 + ln*8 + hf*4 (+j). 4 consecutive kv per b64 write.
#pragma unroll
      for (int g = 0; g < 4; ++g) {
        bf16x4 pk;
#pragma unroll
        for (int j = 0; j < 4; ++j) {
          const float p = __expf(st[g * 4 + j]);
          lpart += p;
          pk[j] = (bf16)p;
        }
        *(bf16x4*)&Pw[g * 256 + ln * 8 + hf * 4] = pk;
      }
      lgkm0();  // P writes visible (wave-private)

      // pb[cl] = B-frag of P^T for kv chunk cl (operand-ready, b128)
      const bf16x8 pb0 = *(const bf16x8*)&Pw[lane * 8];
      const bf16x8 pb1 = *(const bf16x8*)&Pw[512 + lane * 8];
      lgkm0();  // reads retired before next mt overwrites Pw

      // O^T += V^T . P^T  (A = V frags, c_global = mt*2 + cl)
#pragma unroll
      for (int vt = 0; vt < 2; ++vt) {
        oacc[vt] = mfma32(
            *(const bf16x8*)&Vs[(vt * 4 + mt * 2 + 0) * 512 + lane * 8], pb0,
            oacc[vt]);
        oacc[vt] = mfma32(
            *(const bf16x8*)&Vs[(vt * 4 + mt * 2 + 1) * 512 + lane * 8], pb1,
            oacc[vt]);
      }
    }
    __syncthreads();  // all reads retired before next iter's staging
  }

  // ---- kv-half combine (deferred softmax => partials just add) ----
  float* Ocmb = (float*)smem;            // 4 qi x 32 x 64 f32 = 32 KB
  float* Lcmb = (float*)(smem + 32768);  // 4 qi x 64 f32
  if (ki == 1) {
#pragma unroll
    for (int vt = 0; vt < 2; ++vt)
#pragma unroll
      for (int r = 0; r < 16; ++r)
        Ocmb[qi * 2048 + (vt * 16 + r) * 64 + lane] = oacc[vt][r];
    Lcmb[qi * 64 + lane] = lpart;
  }
  __syncthreads();
  if (ki == 0) {
#pragma unroll
    for (int vt = 0; vt < 2; ++vt)
#pragma unroll
      for (int r = 0; r < 16; ++r)
        oacc[vt][r] += Ocmb[qi * 2048 + (vt * 16 + r) * 64 + lane];
    lpart += Lcmb[qi * 64 + lane];

    // lane-halves hold disjoint kv subsets of the same q
    lpart += __shfl_xor(lpart, 32);
    const float inv = 1.0f / lpart;

    // O^T C-layout: q = ln, d = vt*32 + g*8 + hf*4 + j; Og row-major [s][E]
    bf16* orow = Og + ((size_t)b * S + (size_t)tq * 32 + ln) * E + h * 64;
#pragma unroll
    for (int vt = 0; vt < 2; ++vt) {
#pragma unroll
      for (int g = 0; g < 4; ++g) {
        bf16x4 o;
#pragma unroll
        for (int j = 0; j < 4; ++j) o[j] = (bf16)(oacc[vt][g * 4 + j] * inv);
        *(bf16x4*)&orow[vt * 32 + g * 8 + hf * 4] = o;
      }
    }
  }
}

// ---------------------------------------------------------------------------
extern "C" void kernel_launch(void* const* d_in, const int* in_sizes, int n_in,
                              void* d_out, int out_size, void* d_ws, size_t ws_size,
                              hipStream_t stream) {
  const float* x = (const float*)d_in[0];
  const float* Wq = (const float*)d_in[1];
  const float* bq = (const float*)d_in[2];
  const float* Wk = (const float*)d_in[3];
  const float* bk = (const float*)d_in[4];
  const float* Wv = (const float*)d_in[5];
  const float* bv = (const float*)d_in[6];
  const float* Wo = (const float*)d_in[7];
  const float* bo = (const float*)d_in[8];

  const size_t ME = (size_t)4096 * 1024;  // 4M elems
  const size_t WE = (size_t)1024 * 1024;  // 1M elems
  bf16* xb = (bf16*)d_ws;
  bf16* wqt = xb + ME;
  bf16* wkt = wqt + WE;
  bf16* wvt = wkt + WE;
  bf16* wot = wvt + WE;
  bf16* qb = wot + WE;   // Q frags
  bf16* kb = qb + ME;    // K frags
  bf16* vt = kb + ME;    // V frags
  bf16* ab = vt + ME;    // attn out, row-major [B*S][E]

  cast_x<<<2048, 256, 0, stream>>>(x, xb);
  transpose_cast_w<<<dim3(16, 16, 4), 256, 0, stream>>>(Wq, Wk, Wv, Wo, wqt, wkt,
                                                        wvt, wot);
  gemm_qkv<<<dim3(8, 32, 3), 256, 0, stream>>>(xb, wqt, bq, bk, bv, qb, kb, vt);
  attn_mfma<<<dim3(S / 128, H, 2), 512, 0, stream>>>(qb, kb, vt, ab);
  gemm_wo<<<dim3(8, 64), 256, 0, stream>>>(ab, wot, bo, (float*)d_out);
}